// Round 5
// baseline (294.611 us; speedup 1.0000x reference)
//
#include <hip/hip_runtime.h>
#include <stdint.h>

#define D_MODEL 1024
#define SEQ 2048
#define NBATCH 4

typedef __attribute__((ext_vector_type(4))) float f32x4;
typedef __attribute__((ext_vector_type(8))) __bf16 bf16x8;
typedef __attribute__((ext_vector_type(4))) unsigned short u16x4;

__device__ __forceinline__ float b2f(unsigned short u) {
    union { unsigned int i; float f; } c; c.i = ((unsigned int)u) << 16; return c.f;
}
__device__ __forceinline__ unsigned short f2b(float f) {
    union { float f; unsigned int i; } c; c.f = f;
    unsigned int u = c.i;
    u += 0x7FFFu + ((u >> 16) & 1u);
    return (unsigned short)(u >> 16);
}

__device__ __forceinline__ void glds16(void* lds, const void* g) {
    __builtin_amdgcn_global_load_lds((const __attribute__((address_space(1))) void*)g,
                                     (__attribute__((address_space(3))) void*)lds,
                                     16, 0, 0);
}

// Compiler memory fence (free at runtime): memory ops (ds_read/glds) cannot
// cross it; paired around s_barrier so the compiler can't software-pipeline
// next-iteration LDS reads above the barrier.
__device__ __forceinline__ void cfence() { asm volatile("" ::: "memory"); }

// XCD-aware tile remap (8 XCDs, bid%8 = xcd). Each XCD owns a contiguous
// y-band of height gy/8 across all x,z so its L2 holds only its A-band + the
// shared B panel. Pure permutation; requires gy % 8 == 0 (grids: gy in {16,64}).
__device__ __forceinline__ void xcd_map(int& xx, int& yy, int& zz)
{
    const int gx = gridDim.x, gy = gridDim.y;
    int bid = blockIdx.x + gx * (blockIdx.y + gy * blockIdx.z);
    const int H = gy >> 3;
    const int xcd = bid & 7;
    int slot = bid >> 3;
    yy = xcd * H + (slot % H);
    slot /= H;
    xx = slot % gx;
    zz = slot / gx;
}

// ---------------------------------------------------------------------------
// GEMM core: BK=32, 3-deep LDS ring, COUNTED-vmcnt pipeline (T3+T4).
// Geometry (staging rows/slots, XOR swizzle, read offsets) is byte-identical
// to the round-2 harness-passed BK=32 double-buffer kernel; only the sync
// structure changes. LDS = 3 x 8KB x 2 = 48KB -> 3 blocks/CU.
//
// Per iteration ti (br = ti%3, bw = (ti+2)%3):
//   ds_read buf[br]            -> af/bv (tile ti, landed last iteration)
//   stage(tile ti+2 -> buf[bw])   4 x global_load_lds, stay in flight
//   MFMA x16                      (compiler lgkmcnt covers af/bv)
//   s_waitcnt vmcnt(4)            retires tile ti+1's 4 loads ONLY;
//                                 tile ti+2's 4 remain outstanding across
//   sched_barrier(0); s_barrier   the barrier (never drain to 0 mid-loop)
//
// Hazards:
//  RAW: reads at ti+1 need tile ti+1 landed: every wave retired its own 4
//       tile-(ti+1) loads at vmcnt(4) before the barrier; barrier joins all
//       waves -> all portions visible (m201-verified mechanism).
//  WAR: stage at ti writes buf[(ti-1)%3], read at ti-1. Those reads were
//       register-consumed before iter ti-1's MFMA cluster ended (every
//       ds_read has an MFMA consumer; LLVM waits lgkmcnt before use), which
//       precedes iter ti-1's barrier, which precedes this stage.
//  Compiler: cfence pair stops hoisting of memory ops over the barrier;
//       sched_barrier(0) pins the counted waitcnt (rule #18 analog).
// vmcnt(0) occurs exactly once (ti = nt-2).
// ---------------------------------------------------------------------------
__device__ __forceinline__ void gemm_tile(const unsigned short* __restrict__ A,
                                          const unsigned short* __restrict__ Bt,
                                          int K, int m0, int n0,
                                          f32x4 (&acc)[4][4])
{
    __shared__ alignas(16) unsigned short As[3 * 128 * 32];   // 24KB
    __shared__ alignas(16) unsigned short Bs[3 * 128 * 32];   // 24KB

    const int t    = threadIdx.x;                  // 256 threads = 4 waves
    const int wave = t >> 6;
    const int lane = t & 63;

    // staging (round-2 verified): wave w, lane i covers rows
    // {w*16 + i/4, 64 + w*16 + i/4}, slot i&3 holding chunk (i&3)^((row>>1)&3)
    // (row and row+64 share ((row>>1)&3), so one source offset serves both j).
    const int srow = (wave << 4) + (lane >> 2);    // 0..63
    const int sch  = ((lane & 3) ^ ((srow >> 1) & 3)) * 8;

    const unsigned short* Ag = A  + (long)(m0 + srow) * K + sch;
    const unsigned short* Bg = Bt + (long)(n0 + srow) * K + sch;

    char* AsW = (char*)As + wave * 1024;           // wave-uniform glds dest
    char* BsW = (char*)Bs + wave * 1024;

    const int fr = lane & 15, quad = lane >> 4;
    const int wm = (wave >> 1) * 64, wn = (wave & 1) * 64;
    const int slot = (quad ^ ((fr >> 1) & 3)) * 16;   // swizzled read slot
    const int aoff = (wm + fr) * 64 + slot;
    const int boff = (wn + fr) * 64 + slot;

    const int nt = K >> 5;                         // K multiple of 32, nt >= 2

    auto stage = [&](int buf, int ko) {
        #pragma unroll
        for (int j = 0; j < 2; ++j) {
            glds16(AsW + buf * 8192 + j * 4096, Ag + (long)(j * 64) * K + ko);
            glds16(BsW + buf * 8192 + j * 4096, Bg + (long)(j * 64) * K + ko);
        }
    };

    // prologue: tiles 0,1 in flight; retire tile 0 only (tile 1 stays out)
    stage(0, 0);
    stage(1, 32);
    asm volatile("s_waitcnt vmcnt(4)" ::: "memory");
    __builtin_amdgcn_sched_barrier(0);
    cfence(); __builtin_amdgcn_s_barrier(); cfence();

    int br = 0, bw = 2, ko = 64;
    for (int ti = 0; ti < nt; ++ti) {
        const char* Ab = (const char*)As + br * 8192;
        const char* Bb = (const char*)Bs + br * 8192;
        bf16x8 af[4], bv[4];
        #pragma unroll
        for (int i = 0; i < 4; ++i)
            af[i] = *(const bf16x8*)(Ab + aoff + i * 1024);
        #pragma unroll
        for (int i = 0; i < 4; ++i)
            bv[i] = *(const bf16x8*)(Bb + boff + i * 1024);

        const bool pf = (ti + 2 < nt);
        if (pf) { stage(bw, ko); ko += 32; }

        __builtin_amdgcn_s_setprio(1);
        #pragma unroll
        for (int mi = 0; mi < 4; ++mi)
            #pragma unroll
            for (int ni = 0; ni < 4; ++ni)
                acc[mi][ni] = __builtin_amdgcn_mfma_f32_16x16x32_bf16(
                                  af[mi], bv[ni], acc[mi][ni], 0, 0, 0);
        __builtin_amdgcn_s_setprio(0);

        if (pf)               asm volatile("s_waitcnt vmcnt(4)" ::: "memory");
        else if (ti + 1 < nt) asm volatile("s_waitcnt vmcnt(0)" ::: "memory");
        __builtin_amdgcn_sched_barrier(0);
        cfence(); __builtin_amdgcn_s_barrier(); cfence();

        br = (br == 2) ? 0 : br + 1;
        bw = (bw == 2) ? 0 : bw + 1;
    }
}

// Plain-store GEMM, z-batched via element strides. OutT = ushort(bf16) | float.
template<bool BIAS, typename OutT>
__global__ __launch_bounds__(256)
void gemm_bt(const unsigned short* __restrict__ A,
             const unsigned short* __restrict__ Bt,
             const float* __restrict__ bias,
             OutT* __restrict__ C,
             int N, int K, long sA, long sB, long sC)
{
    int xx, yy, zz;
    xcd_map(xx, yy, zz);
    A  += (long)zz * sA;
    Bt += (long)zz * sB;
    C  += (long)zz * sC;
    const int m0 = yy * 128;
    const int n0 = xx * 128;

    f32x4 acc[4][4] = {};
    gemm_tile(A, Bt, K, m0, n0, acc);

    const int t = threadIdx.x, wave = t >> 6, lane = t & 63;
    const int wm = (wave >> 1) * 64, wn = (wave & 1) * 64;
    const int fr = lane & 15, quad = lane >> 4;

    float bb[4] = {0.f, 0.f, 0.f, 0.f};
    if (BIAS) {
        #pragma unroll
        for (int ni = 0; ni < 4; ++ni)
            bb[ni] = bias[n0 + wn + ni * 16 + fr];
    }

    // C/D layout (HW-verified): col = lane&15, row = quad*4 + reg
    #pragma unroll
    for (int mi = 0; mi < 4; ++mi) {
        const int rowb = m0 + wm + mi * 16 + quad * 4;
        #pragma unroll
        for (int ni = 0; ni < 4; ++ni) {
            const int col = n0 + wn + ni * 16 + fr;
            f32x4 v = acc[mi][ni];
            if constexpr (sizeof(OutT) == 4) {
                #pragma unroll
                for (int r = 0; r < 4; ++r)
                    C[(long)(rowb + r) * N + col] = v[r] + bb[ni];
            } else {
                #pragma unroll
                for (int r = 0; r < 4; ++r)
                    C[(long)(rowb + r) * N + col] = (OutT)f2b(v[r] + bb[ni]);
            }
        }
    }
}

// Fused QKV projection: grid (8, 64, 3); remapped z selects weight/bias/output.
// V (z==2) stores transposed per batch: Vt[b][n][s], b = row>>11, s = row&2047.
__global__ __launch_bounds__(256)
void qkv_gemm(const unsigned short* __restrict__ xb,
              const unsigned short* __restrict__ Wqt,
              const unsigned short* __restrict__ Wkt,
              const unsigned short* __restrict__ Wvt,
              const float* __restrict__ bq, const float* __restrict__ bk,
              const float* __restrict__ bv,
              unsigned short* __restrict__ Q, unsigned short* __restrict__ Kb,
              unsigned short* __restrict__ Vt)
{
    int xx, yy, zz;
    xcd_map(xx, yy, zz);

    const unsigned short* Bt; const float* bias; unsigned short* C; bool tstore = false;
    switch (zz) {
        case 0:  Bt = Wqt; bias = bq; C = Q;  break;
        case 1:  Bt = Wkt; bias = bk; C = Kb; break;
        default: Bt = Wvt; bias = bv; C = Vt; tstore = true; break;
    }
    const int m0 = yy * 128;
    const int n0 = xx * 128;
    const int N = D_MODEL, K = D_MODEL;

    f32x4 acc[4][4] = {};
    gemm_tile(xb, Bt, K, m0, n0, acc);

    const int t = threadIdx.x, wave = t >> 6, lane = t & 63;
    const int wm = (wave >> 1) * 64, wn = (wave & 1) * 64;
    const int fr = lane & 15, quad = lane >> 4;

    float bb[4];
    #pragma unroll
    for (int ni = 0; ni < 4; ++ni)
        bb[ni] = bias[n0 + wn + ni * 16 + fr];

    #pragma unroll
    for (int mi = 0; mi < 4; ++mi) {
        const int rowb = m0 + wm + mi * 16 + quad * 4;
        #pragma unroll
        for (int ni = 0; ni < 4; ++ni) {
            const int col = n0 + wn + ni * 16 + fr;
            f32x4 v = acc[mi][ni];
            if (!tstore) {
                #pragma unroll
                for (int r = 0; r < 4; ++r)
                    C[(long)(rowb + r) * N + col] = f2b(v[r] + bb[ni]);
            } else {
                u16x4 pk;
                #pragma unroll
                for (int r = 0; r < 4; ++r)
                    pk[r] = f2b(v[r] + bb[ni]);
                unsigned short* dst = C + ((long)(rowb >> 11)) * ((long)N * SEQ)
                                        + (long)col * SEQ + (rowb & (SEQ - 1));
                *(u16x4*)dst = pk;
            }
        }
    }
}

// In-place softmax over rows of 2048 bf16 raw scores, 1/sqrt(1024) folded in.
__global__ __launch_bounds__(256)
void softmax_inplace(unsigned short* __restrict__ S)
{
    const long row = blockIdx.x;
    unsigned short* s = S + row * SEQ;
    const int t = threadIdx.x;

    u16x4 a = ((const u16x4*)s)[t];
    u16x4 b = ((const u16x4*)s)[t + 256];
    float v[8];
    #pragma unroll
    for (int i = 0; i < 4; ++i) { v[i] = b2f(a[i]); v[4 + i] = b2f(b[i]); }

    float mx = v[0];
    #pragma unroll
    for (int i = 1; i < 8; ++i) mx = fmaxf(mx, v[i]);
    #pragma unroll
    for (int off = 32; off; off >>= 1) mx = fmaxf(mx, __shfl_xor(mx, off));

    __shared__ float red[8];
    const int wv = t >> 6, ln = t & 63;
    if (ln == 0) red[wv] = mx;
    __syncthreads();
    mx = fmaxf(fmaxf(red[0], red[1]), fmaxf(red[2], red[3]));

    const float sc = 0.03125f;
    float e[8], sum = 0.f;
    #pragma unroll
    for (int i = 0; i < 8; ++i) { e[i] = __expf((v[i] - mx) * sc); sum += e[i]; }
    #pragma unroll
    for (int off = 32; off; off >>= 1) sum += __shfl_xor(sum, off);
    if (ln == 0) red[4 + wv] = sum;
    __syncthreads();
    sum = (red[4] + red[5]) + (red[6] + red[7]);
    const float inv = 1.f / sum;

    u16x4 o;
    #pragma unroll
    for (int i = 0; i < 4; ++i) o[i] = f2b(e[i] * inv);
    ((u16x4*)s)[t] = o;
    #pragma unroll
    for (int i = 0; i < 4; ++i) o[i] = f2b(e[4 + i] * inv);
    ((u16x4*)s)[t + 256] = o;
}

// Fused prep: blocks [0,8192) cast x fp32->bf16 (1024 elems each);
// blocks [8192,12288) transpose+cast the four weights (32x32 tiles).
__global__ __launch_bounds__(256)
void prep(const float* __restrict__ x, unsigned short* __restrict__ xb,
          const float* __restrict__ W0, const float* __restrict__ W1,
          const float* __restrict__ W2, const float* __restrict__ W3,
          unsigned short* __restrict__ T0, unsigned short* __restrict__ T1,
          unsigned short* __restrict__ T2, unsigned short* __restrict__ T3)
{
    const int bid = blockIdx.x;
    if (bid < 8192) {
        long i = ((long)bid * 256 + threadIdx.x) * 4;
        f32x4 v = *(const f32x4*)(x + i);
        u16x4 o;
        #pragma unroll
        for (int r = 0; r < 4; ++r) o[r] = f2b(v[r]);
        *(u16x4*)(xb + i) = o;
        return;
    }
    const int b2 = bid - 8192;
    const float* W; unsigned short* T;
    switch (b2 >> 10) {
        case 0:  W = W0; T = T0; break;
        case 1:  W = W1; T = T1; break;
        case 2:  W = W2; T = T2; break;
        default: W = W3; T = T3; break;
    }
    const int tile = b2 & 1023;
    const int bx = (tile & 31) * 32, by = (tile >> 5) * 32;
    __shared__ float buf[32][33];
    const int tx = threadIdx.x & 31, ty = threadIdx.x >> 5;
    #pragma unroll
    for (int i = 0; i < 32; i += 8)
        buf[ty + i][tx] = W[(long)(by + ty + i) * D_MODEL + bx + tx];
    __syncthreads();
    #pragma unroll
    for (int i = 0; i < 32; i += 8)
        T[(long)(bx + ty + i) * D_MODEL + by + tx] = f2b(buf[tx][ty + i]);
}

extern "C" void kernel_launch(void* const* d_in, const int* in_sizes, int n_in,
                              void* d_out, int out_size, void* d_ws, size_t ws_size,
                              hipStream_t stream)
{
    const float* x  = (const float*)d_in[0];
    const float* Wq = (const float*)d_in[1];
    const float* bq = (const float*)d_in[2];
    const float* Wk = (const float*)d_in[3];
    const float* bk = (const float*)d_in[4];
    const float* Wv = (const float*)d_in[5];
    const float* bv = (const float*)d_in[6];
    const float* Wo = (const float*)d_in[7];
    const float* bo = (const float*)d_in[8];
    float* out = (float*)d_out;

    char* ws = (char*)d_ws;
    const size_t MB = 1024ull * 1024ull;
    unsigned short* Wqt = (unsigned short*)(ws + 0 * MB);
    unsigned short* Wkt = (unsigned short*)(ws + 2 * MB);
    unsigned short* Wvt = (unsigned short*)(ws + 4 * MB);
    unsigned short* Wot = (unsigned short*)(ws + 6 * MB);
    unsigned short* xb  = (unsigned short*)(ws + 8 * MB);    // 16MB
    unsigned short* Q   = (unsigned short*)(ws + 24 * MB);   // 16MB
    unsigned short* Kb  = (unsigned short*)(ws + 40 * MB);   // 16MB
    unsigned short* Vt  = (unsigned short*)(ws + 56 * MB);   // 16MB
    unsigned short* At  = (unsigned short*)(ws + 72 * MB);   // 16MB
    unsigned short* S   = (unsigned short*)(ws + 88 * MB);   // 32MB -> 120MB

    const dim3 blk(256);

    prep<<<dim3(12288), blk, 0, stream>>>(x, xb, Wq, Wk, Wv, Wo, Wqt, Wkt, Wvt, Wot);

    qkv_gemm<<<dim3(8, 64, 3), blk, 0, stream>>>(xb, Wqt, Wkt, Wvt, bq, bk, bv, Q, Kb, Vt);

    // scores[b] = Q[b] @ K[b]^T (raw; scale folded into softmax)
    gemm_bt<false, unsigned short><<<dim3(16, 16, 4), blk, 0, stream>>>(
        Q, Kb, nullptr, S, 2048, 1024,
        (long)2048 * 1024, (long)2048 * 1024, (long)2048 * 2048);

    softmax_inplace<<<dim3(NBATCH * SEQ), blk, 0, stream>>>(S);

    // attn[b] = P[b] @ V[b]
    gemm_bt<false, unsigned short><<<dim3(8, 16, 4), blk, 0, stream>>>(
        S, Vt, nullptr, At, 1024, 2048,
        (long)2048 * 2048, (long)1024 * 2048, (long)2048 * 1024);

    // out = attn @ Wo + bo (fp32 store)
    gemm_bt<true, float><<<dim3(8, 64, 1), blk, 0, stream>>>(
        At, Wot, bo, out, 1024, 1024, 0, 0, 0);
}

// Round 6
// 278.198 us; speedup vs baseline: 1.0590x; 1.0590x over previous
//
#include <hip/hip_runtime.h>
#include <stdint.h>

#define D_MODEL 1024
#define SEQ 2048
#define NBATCH 4

typedef __attribute__((ext_vector_type(4))) float f32x4;
typedef __attribute__((ext_vector_type(8))) __bf16 bf16x8;
typedef __attribute__((ext_vector_type(4))) unsigned short u16x4;

__device__ __forceinline__ float b2f(unsigned short u) {
    union { unsigned int i; float f; } c; c.i = ((unsigned int)u) << 16; return c.f;
}
__device__ __forceinline__ unsigned short f2b(float f) {
    union { float f; unsigned int i; } c; c.f = f;
    unsigned int u = c.i;
    u += 0x7FFFu + ((u >> 16) & 1u);
    return (unsigned short)(u >> 16);
}

__device__ __forceinline__ void glds16(void* lds, const void* g) {
    __builtin_amdgcn_global_load_lds((const __attribute__((address_space(1))) void*)g,
                                     (__attribute__((address_space(3))) void*)lds,
                                     16, 0, 0);
}

// Compiler memory fence (free at runtime) paired around s_barrier so the
// compiler cannot move LDS/global memory ops across the barrier.
__device__ __forceinline__ void cfence() { asm volatile("" ::: "memory"); }

// XCD-aware tile remap (8 XCDs, bid%8 = xcd). Each XCD owns a contiguous
// y-band across all x,z. Pure permutation; requires gy % 8 == 0
// (grids here: gy in {8, 32}).
__device__ __forceinline__ void xcd_map(int& xx, int& yy, int& zz)
{
    const int gx = gridDim.x, gy = gridDim.y;
    int bid = blockIdx.x + gx * (blockIdx.y + gy * blockIdx.z);
    const int H = gy >> 3;
    const int xcd = bid & 7;
    int slot = bid >> 3;
    yy = xcd * H + (slot % H);
    slot /= H;
    xx = slot % gx;
    zz = slot / gx;
}

// ---------------------------------------------------------------------------
// GEMM core: BM=256, BN=128, BK=32, 512 threads (8 waves, 4Mx2N, each wave a
// 64x64 sub-tile = the r2/r4-verified per-wave code). 3-deep LDS ring,
// counted-vmcnt pipeline (r5's harness-passed sync skeleton, S=3):
//
// Per iteration ti (br = ti%3, bw = (ti+2)%3):
//   ds_read buf[br] (8 x b128)  -> af/bv (tile ti, landed last iteration)
//   stage(tile ti+2 -> buf[bw])    3 x global_load_lds, stay in flight
//   16 MFMA                        (compiler lgkmcnt covers af/bv)
//   s_waitcnt vmcnt(3)             retires tile ti+1's 3 loads ONLY; the 3
//                                  just-issued remain outstanding across
//   sched_barrier(0); s_barrier    the barrier (never drain mid-loop)
//
// Hazards (same ledger as r5, which passed graph-replay screening):
//  RAW: reads at ti+1 need tile ti+1 landed: every wave retired its own 3
//       tile-(ti+1) loads at vmcnt(3) before the barrier; barrier joins all.
//  WAR: stage at ti writes buf[(ti-1)%3]; its reads were register-consumed
//       (lgkmcnt before MFMA) before iter ti-1's barrier.
//  vmcnt(0) occurs exactly once (ti = nt-2).
//
// Occupancy: LDS = 3*(16KB A + 8KB B) = 72KB -> 2 blocks/CU = 16 waves/CU
// (vs r4's 6 measured) — the latency-hiding this round is betting on.
// LDS layout: [rows][32 cols] bf16, 64B rows, 4x16B slots. XOR swizzle:
// slot s of row r holds chunk s^((r>>1)&3), applied on the glds *source*
// (LDS writes linear) and on the ds_read slot (r2-verified; 0 conflicts).
// ---------------------------------------------------------------------------
__device__ __forceinline__ void gemm_tile(const unsigned short* __restrict__ A,
                                          const unsigned short* __restrict__ Bt,
                                          int K, int m0, int n0,
                                          f32x4 (&acc)[4][4])
{
    __shared__ alignas(16) unsigned short As[3 * 256 * 32];   // 48KB
    __shared__ alignas(16) unsigned short Bs[3 * 128 * 32];   // 24KB

    const int t    = threadIdx.x;                  // 512 threads = 8 waves
    const int wave = t >> 6;
    const int lane = t & 63;

    // Staging: per glds statement a wave covers 16 rows (64 lanes x 16B /
    // 64B-row). A statement jA in {0,1}: rows wave*16 + jA*128 + lane/4;
    // B: rows wave*16 + lane/4. Chunk swizzle (lane&3)^((row>>1)&3); note
    // +128 rows doesn't change ((row>>1)&3), and rB==rA0, so one offset
    // serves all three statements.
    const int srow = (wave << 4) + (lane >> 2);    // 0..127
    const int sch  = ((lane & 3) ^ ((srow >> 1) & 3)) * 8;

    const unsigned short* Ag = A  + (long)(m0 + srow) * K + sch;
    const unsigned short* Bg = Bt + (long)(n0 + srow) * K + sch;

    char* AsW = (char*)As + wave * 1024;           // wave-uniform glds dest
    char* BsW = (char*)Bs + wave * 1024;

    const int fr = lane & 15, quad = lane >> 4;
    const int wr = wave >> 1, wc = wave & 1;       // 4M x 2N wave grid
    const int slot = (quad ^ ((fr >> 1) & 3)) * 16;   // swizzled read slot
    const int aoff = (wr * 64 + fr) * 64 + slot;
    const int boff = (wc * 64 + fr) * 64 + slot;

    const int nt = K >> 5;                         // K multiple of 32, nt >= 3

    auto stage = [&](int buf, int ko) {
        glds16(AsW + buf * 16384,        Ag + ko);
        glds16(AsW + buf * 16384 + 8192, Ag + (long)128 * K + ko);
        glds16(BsW + buf * 8192,         Bg + ko);
    };

    // prologue: tiles 0,1 in flight; retire tile 0 only (tile 1 stays out)
    stage(0, 0);
    stage(1, 32);
    asm volatile("s_waitcnt vmcnt(3)" ::: "memory");
    __builtin_amdgcn_sched_barrier(0);
    cfence(); __builtin_amdgcn_s_barrier(); cfence();

    int br = 0, bw = 2, ko = 64;
    for (int ti = 0; ti < nt; ++ti) {
        const char* Ab = (const char*)As + br * 16384;
        const char* Bb = (const char*)Bs + br * 8192;
        bf16x8 af[4], bv[4];
        #pragma unroll
        for (int i = 0; i < 4; ++i)
            af[i] = *(const bf16x8*)(Ab + aoff + i * 1024);
        #pragma unroll
        for (int i = 0; i < 4; ++i)
            bv[i] = *(const bf16x8*)(Bb + boff + i * 1024);

        const bool pf = (ti + 2 < nt);
        if (pf) { stage(bw, ko); ko += 32; }

        __builtin_amdgcn_s_setprio(1);
        #pragma unroll
        for (int mi = 0; mi < 4; ++mi)
            #pragma unroll
            for (int ni = 0; ni < 4; ++ni)
                acc[mi][ni] = __builtin_amdgcn_mfma_f32_16x16x32_bf16(
                                  af[mi], bv[ni], acc[mi][ni], 0, 0, 0);
        __builtin_amdgcn_s_setprio(0);

        if (pf)               asm volatile("s_waitcnt vmcnt(3)" ::: "memory");
        else if (ti + 1 < nt) asm volatile("s_waitcnt vmcnt(0)" ::: "memory");
        __builtin_amdgcn_sched_barrier(0);
        cfence(); __builtin_amdgcn_s_barrier(); cfence();

        br = (br == 2) ? 0 : br + 1;
        bw = (bw == 2) ? 0 : bw + 1;
    }
}

// Plain-store GEMM, z-batched via element strides. OutT = ushort(bf16) | float.
template<bool BIAS, typename OutT>
__global__ __launch_bounds__(512)
void gemm_bt(const unsigned short* __restrict__ A,
             const unsigned short* __restrict__ Bt,
             const float* __restrict__ bias,
             OutT* __restrict__ C,
             int N, int K, long sA, long sB, long sC)
{
    int xx, yy, zz;
    xcd_map(xx, yy, zz);
    A  += (long)zz * sA;
    Bt += (long)zz * sB;
    C  += (long)zz * sC;
    const int m0 = yy * 256;
    const int n0 = xx * 128;

    f32x4 acc[4][4] = {};
    gemm_tile(A, Bt, K, m0, n0, acc);

    const int t = threadIdx.x, wave = t >> 6, lane = t & 63;
    const int wr = wave >> 1, wc = wave & 1;
    const int fr = lane & 15, quad = lane >> 4;

    float bb[4] = {0.f, 0.f, 0.f, 0.f};
    if (BIAS) {
        #pragma unroll
        for (int ni = 0; ni < 4; ++ni)
            bb[ni] = bias[n0 + wc * 64 + ni * 16 + fr];
    }

    // C/D layout (HW-verified): col = lane&15, row = quad*4 + reg
    #pragma unroll
    for (int mi = 0; mi < 4; ++mi) {
        const int rowb = m0 + wr * 64 + mi * 16 + quad * 4;
        #pragma unroll
        for (int ni = 0; ni < 4; ++ni) {
            const int col = n0 + wc * 64 + ni * 16 + fr;
            f32x4 v = acc[mi][ni];
            if constexpr (sizeof(OutT) == 4) {
                #pragma unroll
                for (int r = 0; r < 4; ++r)
                    C[(long)(rowb + r) * N + col] = v[r] + bb[ni];
            } else {
                #pragma unroll
                for (int r = 0; r < 4; ++r)
                    C[(long)(rowb + r) * N + col] = (OutT)f2b(v[r] + bb[ni]);
            }
        }
    }
}

// Fused QKV projection: grid (8, 32, 3); remapped z selects weight/bias/output.
// V (z==2) stores transposed per batch: Vt[b][n][s], b = row>>11, s = row&2047.
__global__ __launch_bounds__(512)
void qkv_gemm(const unsigned short* __restrict__ xb,
              const unsigned short* __restrict__ Wqt,
              const unsigned short* __restrict__ Wkt,
              const unsigned short* __restrict__ Wvt,
              const float* __restrict__ bq, const float* __restrict__ bk,
              const float* __restrict__ bv,
              unsigned short* __restrict__ Q, unsigned short* __restrict__ Kb,
              unsigned short* __restrict__ Vt)
{
    int xx, yy, zz;
    xcd_map(xx, yy, zz);

    const unsigned short* Bt; const float* bias; unsigned short* C; bool tstore = false;
    switch (zz) {
        case 0:  Bt = Wqt; bias = bq; C = Q;  break;
        case 1:  Bt = Wkt; bias = bk; C = Kb; break;
        default: Bt = Wvt; bias = bv; C = Vt; tstore = true; break;
    }
    const int m0 = yy * 256;
    const int n0 = xx * 128;
    const int N = D_MODEL, K = D_MODEL;

    f32x4 acc[4][4] = {};
    gemm_tile(xb, Bt, K, m0, n0, acc);

    const int t = threadIdx.x, wave = t >> 6, lane = t & 63;
    const int wr = wave >> 1, wc = wave & 1;
    const int fr = lane & 15, quad = lane >> 4;

    float bb[4];
    #pragma unroll
    for (int ni = 0; ni < 4; ++ni)
        bb[ni] = bias[n0 + wc * 64 + ni * 16 + fr];

    #pragma unroll
    for (int mi = 0; mi < 4; ++mi) {
        const int rowb = m0 + wr * 64 + mi * 16 + quad * 4;
        #pragma unroll
        for (int ni = 0; ni < 4; ++ni) {
            const int col = n0 + wc * 64 + ni * 16 + fr;
            f32x4 v = acc[mi][ni];
            if (!tstore) {
                #pragma unroll
                for (int r = 0; r < 4; ++r)
                    C[(long)(rowb + r) * N + col] = f2b(v[r] + bb[ni]);
            } else {
                u16x4 pk;
                #pragma unroll
                for (int r = 0; r < 4; ++r)
                    pk[r] = f2b(v[r] + bb[ni]);
                unsigned short* dst = C + ((long)(rowb >> 11)) * ((long)N * SEQ)
                                        + (long)col * SEQ + (rowb & (SEQ - 1));
                *(u16x4*)dst = pk;
            }
        }
    }
}

// In-place softmax over rows of 2048 bf16 raw scores, 1/sqrt(1024) folded in.
__global__ __launch_bounds__(256)
void softmax_inplace(unsigned short* __restrict__ S)
{
    const long row = blockIdx.x;
    unsigned short* s = S + row * SEQ;
    const int t = threadIdx.x;

    u16x4 a = ((const u16x4*)s)[t];
    u16x4 b = ((const u16x4*)s)[t + 256];
    float v[8];
    #pragma unroll
    for (int i = 0; i < 4; ++i) { v[i] = b2f(a[i]); v[4 + i] = b2f(b[i]); }

    float mx = v[0];
    #pragma unroll
    for (int i = 1; i < 8; ++i) mx = fmaxf(mx, v[i]);
    #pragma unroll
    for (int off = 32; off; off >>= 1) mx = fmaxf(mx, __shfl_xor(mx, off));

    __shared__ float red[8];
    const int wv = t >> 6, ln = t & 63;
    if (ln == 0) red[wv] = mx;
    __syncthreads();
    mx = fmaxf(fmaxf(red[0], red[1]), fmaxf(red[2], red[3]));

    const float sc = 0.03125f;
    float e[8], sum = 0.f;
    #pragma unroll
    for (int i = 0; i < 8; ++i) { e[i] = __expf((v[i] - mx) * sc); sum += e[i]; }
    #pragma unroll
    for (int off = 32; off; off >>= 1) sum += __shfl_xor(sum, off);
    if (ln == 0) red[4 + wv] = sum;
    __syncthreads();
    sum = (red[4] + red[5]) + (red[6] + red[7]);
    const float inv = 1.f / sum;

    u16x4 o;
    #pragma unroll
    for (int i = 0; i < 4; ++i) o[i] = f2b(e[i] * inv);
    ((u16x4*)s)[t] = o;
    #pragma unroll
    for (int i = 0; i < 4; ++i) o[i] = f2b(e[4 + i] * inv);
    ((u16x4*)s)[t + 256] = o;
}

// Fused prep: blocks [0,8192) cast x fp32->bf16 (1024 elems each);
// blocks [8192,12288) transpose+cast the four weights (32x32 tiles).
__global__ __launch_bounds__(256)
void prep(const float* __restrict__ x, unsigned short* __restrict__ xb,
          const float* __restrict__ W0, const float* __restrict__ W1,
          const float* __restrict__ W2, const float* __restrict__ W3,
          unsigned short* __restrict__ T0, unsigned short* __restrict__ T1,
          unsigned short* __restrict__ T2, unsigned short* __restrict__ T3)
{
    const int bid = blockIdx.x;
    if (bid < 8192) {
        long i = ((long)bid * 256 + threadIdx.x) * 4;
        f32x4 v = *(const f32x4*)(x + i);
        u16x4 o;
        #pragma unroll
        for (int r = 0; r < 4; ++r) o[r] = f2b(v[r]);
        *(u16x4*)(xb + i) = o;
        return;
    }
    const int b2 = bid - 8192;
    const float* W; unsigned short* T;
    switch (b2 >> 10) {
        case 0:  W = W0; T = T0; break;
        case 1:  W = W1; T = T1; break;
        case 2:  W = W2; T = T2; break;
        default: W = W3; T = T3; break;
    }
    const int tile = b2 & 1023;
    const int bx = (tile & 31) * 32, by = (tile >> 5) * 32;
    __shared__ float buf[32][33];
    const int tx = threadIdx.x & 31, ty = threadIdx.x >> 5;
    #pragma unroll
    for (int i = 0; i < 32; i += 8)
        buf[ty + i][tx] = W[(long)(by + ty + i) * D_MODEL + bx + tx];
    __syncthreads();
    #pragma unroll
    for (int i = 0; i < 32; i += 8)
        T[(long)(bx + ty + i) * D_MODEL + by + tx] = f2b(buf[tx][ty + i]);
}

extern "C" void kernel_launch(void* const* d_in, const int* in_sizes, int n_in,
                              void* d_out, int out_size, void* d_ws, size_t ws_size,
                              hipStream_t stream)
{
    const float* x  = (const float*)d_in[0];
    const float* Wq = (const float*)d_in[1];
    const float* bq = (const float*)d_in[2];
    const float* Wk = (const float*)d_in[3];
    const float* bk = (const float*)d_in[4];
    const float* Wv = (const float*)d_in[5];
    const float* bv = (const float*)d_in[6];
    const float* Wo = (const float*)d_in[7];
    const float* bo = (const float*)d_in[8];
    float* out = (float*)d_out;

    char* ws = (char*)d_ws;
    const size_t MB = 1024ull * 1024ull;
    unsigned short* Wqt = (unsigned short*)(ws + 0 * MB);
    unsigned short* Wkt = (unsigned short*)(ws + 2 * MB);
    unsigned short* Wvt = (unsigned short*)(ws + 4 * MB);
    unsigned short* Wot = (unsigned short*)(ws + 6 * MB);
    unsigned short* xb  = (unsigned short*)(ws + 8 * MB);    // 16MB
    unsigned short* Q   = (unsigned short*)(ws + 24 * MB);   // 16MB
    unsigned short* Kb  = (unsigned short*)(ws + 40 * MB);   // 16MB
    unsigned short* Vt  = (unsigned short*)(ws + 56 * MB);   // 16MB
    unsigned short* At  = (unsigned short*)(ws + 72 * MB);   // 16MB
    unsigned short* S   = (unsigned short*)(ws + 88 * MB);   // 32MB -> 120MB

    const dim3 blk256(256);
    const dim3 blk512(512);

    prep<<<dim3(12288), blk256, 0, stream>>>(x, xb, Wq, Wk, Wv, Wo, Wqt, Wkt, Wvt, Wot);

    qkv_gemm<<<dim3(8, 32, 3), blk512, 0, stream>>>(xb, Wqt, Wkt, Wvt, bq, bk, bv, Q, Kb, Vt);

    // scores[b] = Q[b] @ K[b]^T (raw; scale folded into softmax)
    gemm_bt<false, unsigned short><<<dim3(16, 8, 4), blk512, 0, stream>>>(
        Q, Kb, nullptr, S, 2048, 1024,
        (long)2048 * 1024, (long)2048 * 1024, (long)2048 * 2048);

    softmax_inplace<<<dim3(NBATCH * SEQ), blk256, 0, stream>>>(S);

    // attn[b] = P[b] @ V[b]
    gemm_bt<false, unsigned short><<<dim3(8, 8, 4), blk512, 0, stream>>>(
        S, Vt, nullptr, At, 1024, 2048,
        (long)2048 * 2048, (long)1024 * 2048, (long)2048 * 1024);

    // out = attn @ Wo + bo (fp32 store)
    gemm_bt<true, float><<<dim3(8, 32, 1), blk512, 0, stream>>>(
        At, Wot, bo, out, 1024, 1024, 0, 0, 0);
}

// Round 8
// 274.129 us; speedup vs baseline: 1.0747x; 1.0148x over previous
//
#include <hip/hip_runtime.h>
#include <stdint.h>

#define D_MODEL 1024
#define SEQ 2048
#define NBATCH 4

typedef __attribute__((ext_vector_type(4))) float f32x4;
typedef __attribute__((ext_vector_type(8))) __bf16 bf16x8;
typedef __attribute__((ext_vector_type(4))) unsigned short u16x4;

__device__ __forceinline__ float b2f(unsigned short u) {
    union { unsigned int i; float f; } c; c.i = ((unsigned int)u) << 16; return c.f;
}
__device__ __forceinline__ unsigned short f2b(float f) {
    union { float f; unsigned int i; } c; c.f = f;
    unsigned int u = c.i;
    u += 0x7FFFu + ((u >> 16) & 1u);
    return (unsigned short)(u >> 16);
}

__device__ __forceinline__ void glds16(void* lds, const void* g) {
    __builtin_amdgcn_global_load_lds((const __attribute__((address_space(1))) void*)g,
                                     (__attribute__((address_space(3))) void*)lds,
                                     16, 0, 0);
}

__device__ __forceinline__ void cfence() { asm volatile("" ::: "memory"); }

#define BAR()   do { cfence(); __builtin_amdgcn_s_barrier(); cfence(); } while (0)
#define LGKM0() do { asm volatile("s_waitcnt lgkmcnt(0)" ::: "memory"); \
                     __builtin_amdgcn_sched_barrier(0); } while (0)
#define VM6()   do { asm volatile("s_waitcnt vmcnt(6)" ::: "memory"); \
                     __builtin_amdgcn_sched_barrier(0); } while (0)
#define VM0()   do { asm volatile("s_waitcnt vmcnt(0)" ::: "memory"); \
                     __builtin_amdgcn_sched_barrier(0); } while (0)
#define PRIO1   __builtin_amdgcn_s_setprio(1)
#define PRIO0   __builtin_amdgcn_s_setprio(0)

// XCD-aware tile remap (8 XCDs, bid%8 = xcd). Pure permutation; requires
// gy % 8 == 0 (grids here: gy in {8, 32}).
__device__ __forceinline__ void xcd_map(int& xx, int& yy, int& zz)
{
    const int gx = gridDim.x, gy = gridDim.y;
    int bid = blockIdx.x + gx * (blockIdx.y + gy * blockIdx.z);
    const int H = gy >> 3;
    const int xcd = bid & 7;
    int slot = bid >> 3;
    yy = xcd * H + (slot % H);
    slot /= H;
    xx = slot % gx;
    zz = slot / gx;
}

// ---------------------------------------------------------------------------
// 4-phase GEMM core, m201-invariant sync: EVERY vm wait sits immediately
// before a barrier; dependent ds_reads are in a LATER phase. BM=256, BN=128,
// BK=64/tile, 512 thr = 8 waves (4M x 2N), per-wave 64x64 = acc[4][4]
// (fragment/swizzle maps verified r4/r6).
//
// LDS: A ring-3 (a0,a1,a2; tile T in ring slot T%3, 32KB each) +
//      B ring-2 (b0,b1; tile T in T%2, 16KB each) = 128KB, 1 block/CU.
//
// Iteration it computes tile E=2it (P0: B-full + A mi0-1; P1: A mi2-3) and
// tile O=2it+1 (P2, P3 likewise). Phase body:
//   ds_read ; stage ; BAR ; LGKM0 ; PRIO1 16xMFMA PRIO0 ; [wait] ; BAR
// Stages (guarded by more = it+1<nIt): P0: A(E+2)->aN; P1: B(E+2)->b0;
//   P2: A(O+2)->aE; P3: B(O+2)->b1.
// Waits: end-P1 vmcnt(6) certifies {A(O) staged prev-P2 (3 phases ago),
//   B(O) staged prev-P3 (2 phases ago)} for P2/P3 reads; end-P3 vmcnt(6)
//   certifies {A(E+2) P0, B(E+2) P1} for next-P0/P1. Ledger: entering P0
//   in-flight = 6 {A(O)4,B(O)2}; +4(P0)+2(P1)=12 -> vmcnt(6) keeps the 6
//   newest {A(E+2),B(E+2)}; +4(P2)+2(P3)=12 -> vmcnt(6) keeps {A(O+2),
//   B(O+2)} = 6. Last iteration: end-P1 wait = vmcnt(0) (nothing staged);
//   no end-P3 wait. vmcnt never drains mid-loop otherwise.
// WAR: each stage target's last readers retired at their own LGKM0 before
//   the preceding end-BAR (P0 tgt aN: last read prev-P3; P1 tgt b0: read P0;
//   P2 tgt aE: read P1; P3 tgt b1: read P2).
// Rotation: next it (aE,aO,aN) <- (aN,aE,aO) — plain pointer swap.
// Swizzle (r4-verified involution): staged slot l&7 of row r holds chunk
//   (l&7)^(r&7) via pre-swizzled source; reader fetches chunk c at slot
//   c^(fr&7). All row offsets are multiples of 8 -> row&7 == fr&7.
// ---------------------------------------------------------------------------
__device__ __forceinline__ void gemm_core(const unsigned short* __restrict__ A,
                                          const unsigned short* __restrict__ Bt,
                                          int K, int m0, int n0,
                                          f32x4 (&acc)[4][4])
{
    __shared__ alignas(16) unsigned short AsR[3 * 256 * 64];   // 96KB
    __shared__ alignas(16) unsigned short BsR[2 * 128 * 64];   // 32KB

    const int t = threadIdx.x, w = t >> 6, l = t & 63;

    // staging map: wave w, lane l -> row w*8 + l/8 of a 64-row statement;
    // pre-swizzled source chunk (l&7)^((l>>3)&7).
    const int srow = (w << 3) + (l >> 3);
    const int sch  = ((l & 7) ^ ((l >> 3) & 7)) * 8;
    const unsigned short* Ag = A  + (long)(m0 + srow) * K + sch;
    const unsigned short* Bg = Bt + (long)(n0 + srow) * K + sch;
    const int woff = w * 1024;                     // wave slice within 8KB stmt

    // read map
    const int fr = l & 15, quad = l >> 4;
    const int wr = w >> 1, wc = w & 1;             // 4M x 2N wave grid
    const int sl0 = ((quad)     ^ (fr & 7)) * 16;
    const int sl1 = ((4 + quad) ^ (fr & 7)) * 16;
    const int aro = wr * 8192 + fr * 128;          // A read base offset
    const int bro = wc * 8192 + fr * 128;          // B read base offset

    char* aE = (char*)AsR;                         // tile 2it
    char* aO = (char*)AsR + 32768;                 // tile 2it+1
    char* aN = (char*)AsR + 65536;                 // stage target (tile 2it+2)
    char* const b0 = (char*)BsR;                   // even tiles
    char* const b1 = (char*)BsR + 16384;           // odd tiles

    const int nIt = K >> 7;                        // K multiple of 128

    auto stageA = [&](char* ab, int kt) {          // full 256x64 A tile: 4 glds
        char* L = ab + woff;
        const unsigned short* g = Ag + (long)kt * 64;
        glds16(L,         g);
        glds16(L +  8192, g + (long)64  * K);
        glds16(L + 16384, g + (long)128 * K);
        glds16(L + 24576, g + (long)192 * K);
    };
    auto stageB = [&](char* bb, int kt) {          // full 128x64 B panel: 2 glds
        char* L = bb + woff;
        const unsigned short* g = Bg + (long)kt * 64;
        glds16(L,        g);
        glds16(L + 8192, g + (long)64 * K);
    };

    bf16x8 bfr[4][2], afr[2][2];

    auto loadB = [&](const char* bb) {
        #pragma unroll
        for (int ni = 0; ni < 4; ++ni) {
            bfr[ni][0] = *(const bf16x8*)(bb + bro + ni * 2048 + sl0);
            bfr[ni][1] = *(const bf16x8*)(bb + bro + ni * 2048 + sl1);
        }
    };
    auto loadA = [&](const char* ab, int mlo) {
        #pragma unroll
        for (int j = 0; j < 2; ++j) {
            afr[j][0] = *(const bf16x8*)(ab + aro + (mlo + j) * 2048 + sl0);
            afr[j][1] = *(const bf16x8*)(ab + aro + (mlo + j) * 2048 + sl1);
        }
    };
    auto mfma16 = [&](int mlo) {
        #pragma unroll
        for (int j = 0; j < 2; ++j)
            #pragma unroll
            for (int ni = 0; ni < 4; ++ni)
                #pragma unroll
                for (int ks = 0; ks < 2; ++ks)
                    acc[mlo + j][ni] = __builtin_amdgcn_mfma_f32_16x16x32_bf16(
                        afr[j][ks], bfr[ni][ks], acc[mlo + j][ni], 0, 0, 0);
    };

    // prologue: A(0),B(0),A(1),B(1) issued (12 loads); vmcnt(6) retires
    // A(0)+B(0) (wait -> BAR -> reads: invariant holds from the start).
    stageA(aE, 0);
    stageB(b0, 0);
    stageA(aO, 1);
    stageB(b1, 1);
    VM6();
    BAR();

    for (int it = 0; it < nIt; ++it) {
        const bool more = (it + 1 < nIt);
        const int tE2 = 2 * it + 2;

        // ---- P0: tile 2it, B-full + A mi0-1 ----
        loadB(b0); loadA(aE, 0);
        if (more) stageA(aN, tE2);
        BAR(); LGKM0();
        PRIO1; mfma16(0); PRIO0;
        BAR();

        // ---- P1: tile 2it, A mi2-3 ----
        loadA(aE, 2);
        if (more) stageB(b0, tE2);
        BAR(); LGKM0();
        PRIO1; mfma16(2); PRIO0;
        if (more) { VM6(); } else { VM0(); }   // certify A(2it+1), B(2it+1)
        BAR();

        // ---- P2: tile 2it+1, B-full + A mi0-1 ----
        loadB(b1); loadA(aO, 0);
        if (more) stageA(aE, tE2 + 1);
        BAR(); LGKM0();
        PRIO1; mfma16(0); PRIO0;
        BAR();

        // ---- P3: tile 2it+1, A mi2-3 ----
        loadA(aO, 2);
        if (more) stageB(b1, tE2 + 1);
        BAR(); LGKM0();
        PRIO1; mfma16(2); PRIO0;
        if (more) VM6();                       // certify A(2it+2), B(2it+2)
        BAR();

        // rotate A ring: (aE, aO, aN) <- (aN, aE, aO)
        char* tmp = aN; aN = aO; aO = aE; aE = tmp;
    }
}

// Plain-store GEMM, z-batched via element strides. OutT = ushort(bf16) | float.
template<bool BIAS, typename OutT>
__global__ __launch_bounds__(512, 2)
void gemm_bt(const unsigned short* __restrict__ A,
             const unsigned short* __restrict__ Bt,
             const float* __restrict__ bias,
             OutT* __restrict__ C,
             int N, int K, long sA, long sB, long sC)
{
    int xx, yy, zz;
    xcd_map(xx, yy, zz);
    A  += (long)zz * sA;
    Bt += (long)zz * sB;
    C  += (long)zz * sC;
    const int m0 = yy * 256;
    const int n0 = xx * 128;

    f32x4 acc[4][4] = {};
    gemm_core(A, Bt, K, m0, n0, acc);

    const int t = threadIdx.x, wave = t >> 6, lane = t & 63;
    const int wr = wave >> 1, wc = wave & 1;
    const int fr = lane & 15, quad = lane >> 4;

    float bb[4] = {0.f, 0.f, 0.f, 0.f};
    if (BIAS) {
        #pragma unroll
        for (int ni = 0; ni < 4; ++ni)
            bb[ni] = bias[n0 + wc * 64 + ni * 16 + fr];
    }

    // C/D layout (HW-verified): col = lane&15, row = quad*4 + reg
    #pragma unroll
    for (int mi = 0; mi < 4; ++mi) {
        const int rowb = m0 + wr * 64 + mi * 16 + quad * 4;
        #pragma unroll
        for (int ni = 0; ni < 4; ++ni) {
            const int col = n0 + wc * 64 + ni * 16 + fr;
            f32x4 v = acc[mi][ni];
            if constexpr (sizeof(OutT) == 4) {
                #pragma unroll
                for (int r = 0; r < 4; ++r)
                    C[(long)(rowb + r) * N + col] = v[r] + bb[ni];
            } else {
                #pragma unroll
                for (int r = 0; r < 4; ++r)
                    C[(long)(rowb + r) * N + col] = (OutT)f2b(v[r] + bb[ni]);
            }
        }
    }
}

// Fused QKV projection: grid (8, 32, 3); remapped z selects weight/bias/output.
// V (z==2) stores transposed per batch: Vt[b][n][s], b = row>>11, s = row&2047.
__global__ __launch_bounds__(512, 2)
void qkv_gemm(const unsigned short* __restrict__ xb,
              const unsigned short* __restrict__ Wqt,
              const unsigned short* __restrict__ Wkt,
              const unsigned short* __restrict__ Wvt,
              const float* __restrict__ bq, const float* __restrict__ bk,
              const float* __restrict__ bv,
              unsigned short* __restrict__ Q, unsigned short* __restrict__ Kb,
              unsigned short* __restrict__ Vt)
{
    int xx, yy, zz;
    xcd_map(xx, yy, zz);

    const unsigned short* Bt; const float* bias; unsigned short* C; bool tstore = false;
    switch (zz) {
        case 0:  Bt = Wqt; bias = bq; C = Q;  break;
        case 1:  Bt = Wkt; bias = bk; C = Kb; break;
        default: Bt = Wvt; bias = bv; C = Vt; tstore = true; break;
    }
    const int m0 = yy * 256;
    const int n0 = xx * 128;
    const int N = D_MODEL, K = D_MODEL;

    f32x4 acc[4][4] = {};
    gemm_core(xb, Bt, K, m0, n0, acc);

    const int t = threadIdx.x, wave = t >> 6, lane = t & 63;
    const int wr = wave >> 1, wc = wave & 1;
    const int fr = lane & 15, quad = lane >> 4;

    float bb[4];
    #pragma unroll
    for (int ni = 0; ni < 4; ++ni)
        bb[ni] = bias[n0 + wc * 64 + ni * 16 + fr];

    #pragma unroll
    for (int mi = 0; mi < 4; ++mi) {
        const int rowb = m0 + wr * 64 + mi * 16 + quad * 4;
        #pragma unroll
        for (int ni = 0; ni < 4; ++ni) {
            const int col = n0 + wc * 64 + ni * 16 + fr;
            f32x4 v = acc[mi][ni];
            if (!tstore) {
                #pragma unroll
                for (int r = 0; r < 4; ++r)
                    C[(long)(rowb + r) * N + col] = f2b(v[r] + bb[ni]);
            } else {
                u16x4 pk;
                #pragma unroll
                for (int r = 0; r < 4; ++r)
                    pk[r] = f2b(v[r] + bb[ni]);
                unsigned short* dst = C + ((long)(rowb >> 11)) * ((long)N * SEQ)
                                        + (long)col * SEQ + (rowb & (SEQ - 1));
                *(u16x4*)dst = pk;
            }
        }
    }
}

// In-place softmax over rows of 2048 bf16 raw scores, 1/sqrt(1024) folded in.
__global__ __launch_bounds__(256)
void softmax_inplace(unsigned short* __restrict__ S)
{
    const long row = blockIdx.x;
    unsigned short* s = S + row * SEQ;
    const int t = threadIdx.x;

    u16x4 a = ((const u16x4*)s)[t];
    u16x4 b = ((const u16x4*)s)[t + 256];
    float v[8];
    #pragma unroll
    for (int i = 0; i < 4; ++i) { v[i] = b2f(a[i]); v[4 + i] = b2f(b[i]); }

    float mx = v[0];
    #pragma unroll
    for (int i = 1; i < 8; ++i) mx = fmaxf(mx, v[i]);
    #pragma unroll
    for (int off = 32; off; off >>= 1) mx = fmaxf(mx, __shfl_xor(mx, off));

    __shared__ float red[8];
    const int wv = t >> 6, ln = t & 63;
    if (ln == 0) red[wv] = mx;
    __syncthreads();
    mx = fmaxf(fmaxf(red[0], red[1]), fmaxf(red[2], red[3]));

    const float sc = 0.03125f;
    float e[8], sum = 0.f;
    #pragma unroll
    for (int i = 0; i < 8; ++i) { e[i] = __expf((v[i] - mx) * sc); sum += e[i]; }
    #pragma unroll
    for (int off = 32; off; off >>= 1) sum += __shfl_xor(sum, off);
    if (ln == 0) red[4 + wv] = sum;
    __syncthreads();
    sum = (red[4] + red[5]) + (red[6] + red[7]);
    const float inv = 1.f / sum;

    u16x4 o;
    #pragma unroll
    for (int i = 0; i < 4; ++i) o[i] = f2b(e[i] * inv);
    ((u16x4*)s)[t] = o;
    #pragma unroll
    for (int i = 0; i < 4; ++i) o[i] = f2b(e[4 + i] * inv);
    ((u16x4*)s)[t + 256] = o;
}

// Fused prep: blocks [0,8192) cast x fp32->bf16 (1024 elems each);
// blocks [8192,12288) transpose+cast the four weights (32x32 tiles).
__global__ __launch_bounds__(256)
void prep(const float* __restrict__ x, unsigned short* __restrict__ xb,
          const float* __restrict__ W0, const float* __restrict__ W1,
          const float* __restrict__ W2, const float* __restrict__ W3,
          unsigned short* __restrict__ T0, unsigned short* __restrict__ T1,
          unsigned short* __restrict__ T2, unsigned short* __restrict__ T3)
{
    const int bid = blockIdx.x;
    if (bid < 8192) {
        long i = ((long)bid * 256 + threadIdx.x) * 4;
        f32x4 v = *(const f32x4*)(x + i);
        u16x4 o;
        #pragma unroll
        for (int r = 0; r < 4; ++r) o[r] = f2b(v[r]);
        *(u16x4*)(xb + i) = o;
        return;
    }
    const int b2 = bid - 8192;
    const float* W; unsigned short* T;
    switch (b2 >> 10) {
        case 0:  W = W0; T = T0; break;
        case 1:  W = W1; T = T1; break;
        case 2:  W = W2; T = T2; break;
        default: W = W3; T = T3; break;
    }
    const int tile = b2 & 1023;
    const int bx = (tile & 31) * 32, by = (tile >> 5) * 32;
    __shared__ float buf[32][33];
    const int tx = threadIdx.x & 31, ty = threadIdx.x >> 5;
    #pragma unroll
    for (int i = 0; i < 32; i += 8)
        buf[ty + i][tx] = W[(long)(by + ty + i) * D_MODEL + bx + tx];
    __syncthreads();
    #pragma unroll
    for (int i = 0; i < 32; i += 8)
        T[(long)(bx + ty + i) * D_MODEL + by + tx] = f2b(buf[tx][ty + i]);
}

extern "C" void kernel_launch(void* const* d_in, const int* in_sizes, int n_in,
                              void* d_out, int out_size, void* d_ws, size_t ws_size,
                              hipStream_t stream)
{
    const float* x  = (const float*)d_in[0];
    const float* Wq = (const float*)d_in[1];
    const float* bq = (const float*)d_in[2];
    const float* Wk = (const float*)d_in[3];
    const float* bk = (const float*)d_in[4];
    const float* Wv = (const float*)d_in[5];
    const float* bv = (const float*)d_in[6];
    const float* Wo = (const float*)d_in[7];
    const float* bo = (const float*)d_in[8];
    float* out = (float*)d_out;

    char* ws = (char*)d_ws;
    const size_t MB = 1024ull * 1024ull;
    unsigned short* Wqt = (unsigned short*)(ws + 0 * MB);
    unsigned short* Wkt = (unsigned short*)(ws + 2 * MB);
    unsigned short* Wvt = (unsigned short*)(ws + 4 * MB);
    unsigned short* Wot = (unsigned short*)(ws + 6 * MB);
    unsigned short* xb  = (unsigned short*)(ws + 8 * MB);    // 16MB
    unsigned short* Q   = (unsigned short*)(ws + 24 * MB);   // 16MB
    unsigned short* Kb  = (unsigned short*)(ws + 40 * MB);   // 16MB
    unsigned short* Vt  = (unsigned short*)(ws + 56 * MB);   // 16MB
    unsigned short* At  = (unsigned short*)(ws + 72 * MB);   // 16MB
    unsigned short* S   = (unsigned short*)(ws + 88 * MB);   // 32MB -> 120MB

    const dim3 blk256(256);
    const dim3 blk512(512);

    prep<<<dim3(12288), blk256, 0, stream>>>(x, xb, Wq, Wk, Wv, Wo, Wqt, Wkt, Wvt, Wot);

    qkv_gemm<<<dim3(8, 32, 3), blk512, 0, stream>>>(xb, Wqt, Wkt, Wvt, bq, bk, bv, Q, Kb, Vt);

    // scores[b] = Q[b] @ K[b]^T (raw; scale folded into softmax)
    gemm_bt<false, unsigned short><<<dim3(16, 8, 4), blk512, 0, stream>>>(
        Q, Kb, nullptr, S, 2048, 1024,
        (long)2048 * 1024, (long)2048 * 1024, (long)2048 * 2048);

    softmax_inplace<<<dim3(NBATCH * SEQ), blk256, 0, stream>>>(S);

    // attn[b] = P[b] @ V[b]
    gemm_bt<false, unsigned short><<<dim3(8, 8, 4), blk512, 0, stream>>>(
        S, Vt, nullptr, At, 1024, 2048,
        (long)2048 * 2048, (long)1024 * 2048, (long)2048 * 1024);

    // out = attn @ Wo + bo (fp32 store)
    gemm_bt<true, float><<<dim3(8, 32, 1), blk512, 0, stream>>>(
        At, Wot, bo, out, 1024, 1024, 0, 0, 0);
}